// Round 9
// baseline (348.326 us; speedup 1.0000x reference)
//
#include <hip/hip_runtime.h>
#include <hip/hip_bf16.h>
#include <cstdint>
#include <cstddef>

// MyBaseRNN: out[t,b,h] = tanh( x[t,b,:]·W[h,:] + ib[h] + h0[b,:]·U[h,:] + hb[h] )
// hidden = out[T-1].  GEMM: M=131072, N=512, K=512.
// R9: stationary-W streaming GEMM. Evidence R1-R8: all barrier-phased
// structures plateau 210-270us regardless of occupancy (42-54%) or
// conflicts (0) -> MLP-limited: loads only in flight during stage bursts
// (vmcnt(0) drain at each barrier). Fix: W-slice (64 cols x 512 k = 64KB)
// stationary in LDS, loaded once (ONE barrier total); 8 waves free-run,
// streaming x global->reg (fp32) with t+1 prefetch always in flight,
// cvt->bf16 in-reg (co-issues with MFMA), B-frags from swizzled LDS.
// No A round-trip, no per-step barrier, ~8KB/wave outstanding forever.

#define T_LEN 2048
#define BATCH 64
#define ISZ 512
#define HSZ 512
#define MTOT (T_LEN * BATCH) /* 131072 */

#define NT 8            /* n-slices */
#define NSL (HSZ / NT)  /* 64 cols per slice */
#define MC 256          /* m-rows per block (8 waves x 32) */
#define NMC (MTOT / MC) /* 512 m-chunks */

typedef __attribute__((ext_vector_type(8))) __bf16 bf16x8;
typedef __attribute__((ext_vector_type(4))) __bf16 bf16x4;
typedef __attribute__((ext_vector_type(4))) float f32x4;

#define GLOBAL_AS __attribute__((address_space(1)))
#define LDS_AS __attribute__((address_space(3)))

__device__ __forceinline__ float fast_tanh(float v) {
    float e = __expf(2.0f * v);
    return 1.0f - 2.0f / (e + 1.0f);
}

// ---------- Kernel 1: fused W->bf16 convert (blocks 0..127) + uh (blocks 128..191) ----
__global__ __launch_bounds__(512) void prep_kernel(const float* __restrict__ W,
                                                   __bf16* __restrict__ Wbf,
                                                   const float* __restrict__ prev,
                                                   const float* __restrict__ U,
                                                   const float* __restrict__ hb,
                                                   const float* __restrict__ ib,
                                                   float* __restrict__ uh) {
    if (blockIdx.x < 128) {
        int i = blockIdx.x * 512 + threadIdx.x; // 65536 f32x4 total
        f32x4 f = ((const f32x4*)W)[i];
        bf16x4 v;
        v[0] = (__bf16)f[0]; v[1] = (__bf16)f[1];
        v[2] = (__bf16)f[2]; v[3] = (__bf16)f[3];
        ((bf16x4*)Wbf)[i] = v;
    } else {
        __shared__ float sp[HSZ];
        int b = blockIdx.x - 128, h = threadIdx.x;
        sp[h] = prev[b * HSZ + h];
        __syncthreads();
        const float* urow = U + (size_t)h * HSZ;
        float acc = 0.f;
#pragma unroll 4
        for (int i = 0; i < HSZ; i += 4) {
            f32x4 u4 = *(const f32x4*)(urow + i);
            acc += u4[0] * sp[i] + u4[1] * sp[i + 1] + u4[2] * sp[i + 2] + u4[3] * sp[i + 3];
        }
        uh[b * HSZ + h] = acc + hb[h] + ib[h];
    }
}

// ---------- Kernel 2: streaming GEMM + bias + tanh (+ fused hidden copy) ----------
// 4096 blocks x 512 threads (8 waves). Block owns 256 m-rows x one 64-col
// n-slice; wave w owns rows [w*32, w*32+32). W-slice stationary in 64KB LDS
// (rows=n 0..63, 1KB each, XOR-swizzled byte col ^= (row&7)<<4).
// acc[2][4] f32x4 = 32 AGPR; aPre[8] f32x4 = 32 VGPR prefetch.
__global__ __launch_bounds__(512, 4) void gemm_tanh_kernel(
        const float* __restrict__ x, const __bf16* __restrict__ Wbf,
        const float* __restrict__ uh, float* __restrict__ out,
        float* __restrict__ hid) {
    __shared__ __attribute__((aligned(16))) char sW[NSL * ISZ * 2]; // 64 KB

    // XCD swizzle: 4096 blocks, runs of 512 per XCD; nt cycles fastest ->
    // the 8 same-m blocks are adjacent on one XCD (x slice L2-shared).
    int orig = blockIdx.x;
    int wg = (orig & 7) * 512 + (orig >> 3);
    int mc = wg >> 3, nt = wg & 7;

    int tid = threadIdx.x;
    int lane = tid & 63, wid = tid >> 6; // 8 waves
    int l15 = lane & 15, l4 = lane >> 4;

    const size_t m0 = (size_t)mc * MC;
    const int n0 = nt * NSL;

    // ---- stage W-slice once: 64 rows x 1KB, pre-swizzled source ----
#pragma unroll
    for (int j = 0; j < 8; ++j) {
        int row = wid * 8 + j; // wave-uniform
        const __bf16* g = Wbf + (size_t)(n0 + row) * ISZ
                        + ((((lane * 16) ^ ((row & 7) << 4))) >> 1);
        __builtin_amdgcn_global_load_lds((const GLOBAL_AS uint32_t*)g,
            (LDS_AS uint32_t*)(sW + row * 1024), 16, 0, 0);
    }
    __syncthreads(); // the ONLY barrier

    // A stream bases: wave rows m0 + wid*32 + mi*16 + l15, lane k-off l4*8
    const float* aB0 = x + (m0 + wid * 32 + l15) * (size_t)ISZ + l4 * 8;
    const float* aB1 = aB0 + 16 * ISZ;

    f32x4 acc[2][4] = {};
    f32x4 aPre[8]; // [mi][kk][half] = aPre[mi*4 + kk*2 + h]

    // prologue: t=0 loads (8 dwordx4 in flight)
#pragma unroll
    for (int kk = 0; kk < 2; ++kk) {
        aPre[kk * 2]     = *(const f32x4*)(aB0 + kk * 32);
        aPre[kk * 2 + 1] = *(const f32x4*)(aB0 + kk * 32 + 4);
        aPre[4 + kk * 2]     = *(const f32x4*)(aB1 + kk * 32);
        aPre[4 + kk * 2 + 1] = *(const f32x4*)(aB1 + kk * 32 + 4);
    }

#pragma unroll 1
    for (int t = 0; t < 8; ++t) {
#pragma unroll
        for (int kk = 0; kk < 2; ++kk) {
            // cvt current A frags, then immediately reissue those slots for t+1
            bf16x8 af[2];
#pragma unroll
            for (int mi = 0; mi < 2; ++mi) {
                f32x4 a0 = aPre[mi * 4 + kk * 2];
                f32x4 a1 = aPre[mi * 4 + kk * 2 + 1];
                bf16x8 v;
                v[0] = (__bf16)a0[0]; v[1] = (__bf16)a0[1];
                v[2] = (__bf16)a0[2]; v[3] = (__bf16)a0[3];
                v[4] = (__bf16)a1[0]; v[5] = (__bf16)a1[1];
                v[6] = (__bf16)a1[2]; v[7] = (__bf16)a1[3];
                af[mi] = v;
            }
            if (t < 7) {
                const float* p0 = aB0 + (t + 1) * 64 + kk * 32;
                const float* p1 = aB1 + (t + 1) * 64 + kk * 32;
                aPre[kk * 2]         = *(const f32x4*)p0;
                aPre[kk * 2 + 1]     = *(const f32x4*)(p0 + 4);
                aPre[4 + kk * 2]     = *(const f32x4*)p1;
                aPre[4 + kk * 2 + 1] = *(const f32x4*)(p1 + 4);
            }
            // B frags from stationary LDS (swizzled read; 2-way banks = free)
            int cbase = t * 128 + kk * 64 + l4 * 16;
#pragma unroll
            for (int ni = 0; ni < 4; ++ni) {
                int row = ni * 16 + l15;
                bf16x8 bfr = *(const bf16x8*)(sW + row * 1024 +
                                              (cbase ^ ((row & 7) << 4)));
#pragma unroll
                for (int mi = 0; mi < 2; ++mi)
                    acc[mi][ni] = __builtin_amdgcn_mfma_f32_16x16x32_bf16(
                        bfr, af[mi], acc[mi][ni], 0, 0, 0);
            }
        }
    }

    // ---- epilogue (no barrier): + uh, tanh, dwordx4 stores.
    // D layout (mfma(bfr, af), proven R1-R8): col = l15 = m-local,
    // row = l4*4 + r = n-local.
#pragma unroll
    for (int mi = 0; mi < 2; ++mi) {
        size_t m = m0 + wid * 32 + mi * 16 + l15;
        int bb = (int)(m & 63);
#pragma unroll
        for (int ni = 0; ni < 4; ++ni) {
            int nb = n0 + ni * 16 + l4 * 4;
            f32x4 u4 = *(const f32x4*)&uh[bb * HSZ + nb];
            f32x4 v;
#pragma unroll
            for (int r = 0; r < 4; ++r) v[r] = fast_tanh(acc[mi][ni][r] + u4[r]);
            *(f32x4*)&out[m * HSZ + nb] = v;
            if (m >= (size_t)(MTOT - BATCH))
                *(f32x4*)&hid[(m - (size_t)(MTOT - BATCH)) * HSZ + nb] = v;
        }
    }
}

extern "C" void kernel_launch(void* const* d_in, const int* in_sizes, int n_in,
                              void* d_out, int out_size, void* d_ws, size_t ws_size,
                              hipStream_t stream) {
    const float* x  = (const float*)d_in[0];
    const float* ph = (const float*)d_in[1];
    const float* W  = (const float*)d_in[2];
    const float* U  = (const float*)d_in[3];
    const float* hb = (const float*)d_in[4];
    const float* ib = (const float*)d_in[5];
    float* out = (float*)d_out;
    float* hid = out + (size_t)MTOT * HSZ;

    __bf16* Wbf = (__bf16*)d_ws;                      // 512 KB
    float* uh   = (float*)((char*)d_ws + 512 * 1024); // 128 KB

    hipLaunchKernelGGL(prep_kernel, dim3(192), dim3(512), 0, stream,
                       W, Wbf, ph, U, hb, ib, uh);
    hipLaunchKernelGGL(gemm_tanh_kernel, dim3(NMC * NT), dim3(512), 0, stream,
                       x, Wbf, uh, out, hid);
}